// Round 4
// baseline (1492.040 us; speedup 1.0000x reference)
//
#include <hip/hip_runtime.h>
#include <hip/hip_bf16.h>
#include <math.h>

#define EMB 128
#define CDIM 12
#define FIN 16
#define NLAYER 5
#define BN_EPS 1e-5f

typedef __attribute__((ext_vector_type(8))) short bf16x8;
typedef __attribute__((ext_vector_type(4))) float f32x4;
typedef unsigned short ushort_t;

__device__ __forceinline__ float bf_lo(unsigned p) { return __uint_as_float(p << 16); }
__device__ __forceinline__ float bf_hi(unsigned p) { return __uint_as_float(p & 0xffff0000u); }

// split y (fp32) into bf16 hi (truncate) + bf16 lo (residual, truncate)
__device__ __forceinline__ void bsplit(float y, unsigned& h16, unsigned& l16) {
    unsigned u = __float_as_uint(y);
    h16 = u >> 16;
    float r = y - __uint_as_float(u & 0xffff0000u);
    l16 = __float_as_uint(r) >> 16;
}

// ---------------- graph preprocessing ----------------

__global__ __launch_bounds__(256) void k_gstart(const int* __restrict__ batch,
                                                int* __restrict__ gs, int N, int G) {
    int i = blockIdx.x * 256 + threadIdx.x;
    if (i >= N) return;
    if (i == 0) gs[0] = 0;
    else { int b = batch[i]; if (b != batch[i - 1]) gs[b] = i; }
    if (i == N - 1) gs[G] = N;
}

__global__ __launch_bounds__(256) void k_zero_i32(int* __restrict__ p, int n) {
    int i = blockIdx.x * 256 + threadIdx.x;
    if (i < n) p[i] = 0;
}

__global__ __launch_bounds__(256) void k_hist(const int* __restrict__ dst, int* __restrict__ cnt, int E) {
    int e = blockIdx.x * 256 + threadIdx.x;
    if (e < E) atomicAdd(&cnt[dst[e]], 1);
}

__global__ __launch_bounds__(256) void k_scan1(const int* __restrict__ cnt, int* __restrict__ rs,
                                               int* __restrict__ partials, int N) {
    __shared__ int tsum[256];
    int t = threadIdx.x;
    int base = blockIdx.x * 1024 + t * 4;
    int c[4];
    #pragma unroll
    for (int j = 0; j < 4; j++) c[j] = (base + j < N) ? cnt[base + j] : 0;
    int s = c[0] + c[1] + c[2] + c[3];
    tsum[t] = s;
    __syncthreads();
    for (int off = 1; off < 256; off <<= 1) {
        int v = (t >= off) ? tsum[t - off] : 0;
        __syncthreads();
        tsum[t] += v;
        __syncthreads();
    }
    int run = tsum[t] - s;
    if (t == 255) partials[blockIdx.x] = tsum[255];
    #pragma unroll
    for (int j = 0; j < 4; j++) {
        if (base + j < N) rs[base + j] = run;
        run += c[j];
    }
}

__global__ __launch_bounds__(256) void k_scan2(int* __restrict__ partials, int NB) {
    __shared__ int tmp[256];
    int t = threadIdx.x;
    int v = (t < NB) ? partials[t] : 0;
    tmp[t] = v;
    __syncthreads();
    for (int off = 1; off < 256; off <<= 1) {
        int u = (t >= off) ? tmp[t - off] : 0;
        __syncthreads();
        tmp[t] += u;
        __syncthreads();
    }
    if (t < NB) partials[t] = tmp[t] - v;
}

__global__ __launch_bounds__(256) void k_scan3(int* __restrict__ rs, const int* __restrict__ partials,
                                               int* __restrict__ cur_off, int N, int E) {
    int t = threadIdx.x;
    int base = blockIdx.x * 1024 + t * 4;
    int add = partials[blockIdx.x];
    #pragma unroll
    for (int j = 0; j < 4; j++) {
        int i = base + j;
        if (i < N) { int v = rs[i] + add; rs[i] = v; cur_off[i] = v; }
    }
    if (blockIdx.x == 0 && t == 0) rs[N] = E;
}

__global__ __launch_bounds__(256) void k_fillslots(const int* __restrict__ src, const int* __restrict__ dst,
                                                   int* __restrict__ cur_off, int* __restrict__ csr_src, int E) {
    int e = blockIdx.x * 256 + threadIdx.x;
    if (e >= E) return;
    int d = dst[e];
    int pos = atomicAdd(&cur_off[d], 1);
    csr_src[pos] = src[e];
}

// ---------------- weight prep: fold BN, transpose, split bf16 hi/lo ----------------
// j = 0..10: 128x128 weights -> WhiT/WloT [f][k] + biasf
// j = 11: init_w1 (16x128) folded fp32 -> W1f + bias1f
// j = 12: ilin_w (128x12, pad to 16) -> WzhiT/WzloT [f][k] + biasz

__global__ __launch_bounds__(256) void k_prep(
        const float* __restrict__ init_w1, const float* __restrict__ init_b1,
        const float* __restrict__ b1s, const float* __restrict__ b1b,
        const float* __restrict__ b1m, const float* __restrict__ b1v,
        const float* __restrict__ init_w2, const float* __restrict__ init_b2,
        const float* __restrict__ i_s, const float* __restrict__ i_b,
        const float* __restrict__ i_m, const float* __restrict__ i_v,
        const float* __restrict__ lw1, const float* __restrict__ lb1,
        const float* __restrict__ l1s, const float* __restrict__ l1b,
        const float* __restrict__ l1m, const float* __restrict__ l1v,
        const float* __restrict__ lw2, const float* __restrict__ lb2,
        const float* __restrict__ l2s, const float* __restrict__ l2b,
        const float* __restrict__ l2m, const float* __restrict__ l2v,
        const float* __restrict__ ilin_w, const float* __restrict__ ilin_b,
        ushort_t* __restrict__ WhiT, ushort_t* __restrict__ WloT, float* __restrict__ biasf,
        float* __restrict__ W1f, float* __restrict__ bias1f,
        ushort_t* __restrict__ WzhiT, ushort_t* __restrict__ WzloT, float* __restrict__ biasz) {
    int j = blockIdx.x;
    int t = threadIdx.x;
    __shared__ float alpha[EMB];

    if (j == 12) {
        if (t < 16) biasz[t] = (t < CDIM) ? ilin_b[t] : 0.f;
        for (int i = t; i < 16 * EMB; i += 256) {
            int f = i >> 7, k = i & 127;
            float w = (f < CDIM) ? ilin_w[k * CDIM + f] : 0.f;
            unsigned h16, l16;
            bsplit(w, h16, l16);
            WzhiT[i] = (ushort_t)h16;
            WzloT[i] = (ushort_t)l16;
        }
        return;
    }
    if (j == 11) {
        if (t < EMB) {
            float a = b1s[t] * rsqrtf(b1v[t] + BN_EPS);
            alpha[t] = a;
            bias1f[t] = init_b1[t] * a + (b1b[t] - b1m[t] * a);
        }
        __syncthreads();
        for (int i = t; i < FIN * EMB; i += 256) W1f[i] = init_w1[i] * alpha[i & 127];
        return;
    }

    const float *W, *lb, *s, *bb, *m, *v;
    if (j == 0)      { W = init_w2;            lb = init_b2;        s = i_s;           bb = i_b;           m = i_m;           v = i_v; }
    else if (j <= 5) { int l = j - 1; W = lw1 + l * 16384; lb = lb1 + l * 128; s = l1s + l * 128; bb = l1b + l * 128; m = l1m + l * 128; v = l1v + l * 128; }
    else             { int l = j - 6; W = lw2 + l * 16384; lb = lb2 + l * 128; s = l2s + l * 128; bb = l2b + l * 128; m = l2m + l * 128; v = l2v + l * 128; }
    if (t < EMB) {
        float a = s[t] * rsqrtf(v[t] + BN_EPS);
        alpha[t] = a;
        biasf[j * EMB + t] = lb[t] * a + (bb[t] - m[t] * a);
    }
    __syncthreads();
    for (int i = t; i < EMB * EMB; i += 256) {
        int k = i >> 7, f = i & 127;
        float w = W[i] * alpha[f];
        unsigned h16, l16;
        bsplit(w, h16, l16);
        WhiT[j * 16384 + f * 128 + k] = (ushort_t)h16;
        WloT[j * 16384 + f * 128 + k] = (ushort_t)l16;
    }
}

// ---------------- init linear: x[N,16] @ W1f[16,128], relu, hi/lo split out ----------------
// thread = (node, 8 feats); 16 nodes / block

__global__ __launch_bounds__(256) void k_lin16(const float* __restrict__ x,
        ushort_t* __restrict__ Ohi, ushort_t* __restrict__ Olo,
        const float* __restrict__ W1f, const float* __restrict__ bias1f, int N) {
    __shared__ float Ws[FIN * EMB];
    for (int i = threadIdx.x; i < FIN * EMB; i += 256) Ws[i] = W1f[i];
    __syncthreads();
    int node = blockIdx.x * 16 + (threadIdx.x >> 4);
    int f0 = (threadIdx.x & 15) * 8;
    if (node >= N) return;
    float4 xq[4];
    #pragma unroll
    for (int q = 0; q < 4; q++) xq[q] = *(const float4*)&x[(size_t)node * FIN + q * 4];
    float xr[16] = {xq[0].x, xq[0].y, xq[0].z, xq[0].w, xq[1].x, xq[1].y, xq[1].z, xq[1].w,
                    xq[2].x, xq[2].y, xq[2].z, xq[2].w, xq[3].x, xq[3].y, xq[3].z, xq[3].w};
    float4 b0 = *(const float4*)&bias1f[f0];
    float4 b1 = *(const float4*)&bias1f[f0 + 4];
    float acc[8] = {b0.x, b0.y, b0.z, b0.w, b1.x, b1.y, b1.z, b1.w};
    #pragma unroll
    for (int k = 0; k < FIN; k++) {
        float xk = xr[k];
        float4 w0 = *(const float4*)&Ws[k * EMB + f0];
        float4 w1 = *(const float4*)&Ws[k * EMB + f0 + 4];
        acc[0] += xk * w0.x; acc[1] += xk * w0.y; acc[2] += xk * w0.z; acc[3] += xk * w0.w;
        acc[4] += xk * w1.x; acc[5] += xk * w1.y; acc[6] += xk * w1.z; acc[7] += xk * w1.w;
    }
    union { ushort_t u[8]; uint4 v; } H, L;
    #pragma unroll
    for (int q = 0; q < 8; q++) {
        float y = fmaxf(acc[q], 0.f);
        unsigned h16, l16;
        bsplit(y, h16, l16);
        H.u[q] = (ushort_t)h16;
        L.u[q] = (ushort_t)l16;
    }
    *(uint4*)&Ohi[(size_t)node * EMB + f0] = H.v;
    *(uint4*)&Olo[(size_t)node * EMB + f0] = L.v;
}

// ---------------- MFMA GEMM: h' = relu(h @ W + b), all bf16 hi/lo ----------------
// Swapped operands: A = W-frag (rows=feats), B = node-frag (cols=nodes)
// => D[feat][node]: lane(col=node, kg) holds feats kg*4..kg*4+3 -> vector stores.

__global__ __launch_bounds__(256) void k_gemm(const ushort_t* __restrict__ Ahi,
        const ushort_t* __restrict__ Alo,
        ushort_t* __restrict__ Ohi, ushort_t* __restrict__ Olo,
        const ushort_t* __restrict__ WhiT, const ushort_t* __restrict__ WloT,
        const float* __restrict__ biasf, int ntiles, int N) {
    const int w = threadIdx.x >> 6;
    const int lane = threadIdx.x & 63;
    const int col = lane & 15, kg = lane >> 4;

    bf16x8 Bh[2][4], Bl[2][4];
    #pragma unroll
    for (int t = 0; t < 2; t++) {
        int f = (w * 2 + t) * 16 + col;
        #pragma unroll
        for (int s = 0; s < 4; s++) {
            int off = f * EMB + s * 32 + kg * 8;
            Bh[t][s] = *(const bf16x8*)(WhiT + off);
            Bl[t][s] = *(const bf16x8*)(WloT + off);
        }
    }
    float4 bvt[2];
    #pragma unroll
    for (int t = 0; t < 2; t++) bvt[t] = *(const float4*)&biasf[(w * 2 + t) * 16 + kg * 4];

    for (int tile = blockIdx.x; tile < ntiles; tile += gridDim.x) {
        int na = min(tile * 16 + col, N - 1);
        const ushort_t* ph = Ahi + (size_t)na * EMB + kg * 8;
        const ushort_t* pl = Alo + (size_t)na * EMB + kg * 8;
        bf16x8 xh[4], xl[4];
        #pragma unroll
        for (int s = 0; s < 4; s++) {
            xh[s] = *(const bf16x8*)(ph + s * 32);
            xl[s] = *(const bf16x8*)(pl + s * 32);
        }
        f32x4 acc[2];
        acc[0] = (f32x4){0.f, 0.f, 0.f, 0.f};
        acc[1] = (f32x4){0.f, 0.f, 0.f, 0.f};
        #pragma unroll
        for (int s = 0; s < 4; s++) {
            #pragma unroll
            for (int t = 0; t < 2; t++) {
                acc[t] = __builtin_amdgcn_mfma_f32_16x16x32_bf16(Bh[t][s], xh[s], acc[t], 0, 0, 0);
                acc[t] = __builtin_amdgcn_mfma_f32_16x16x32_bf16(Bh[t][s], xl[s], acc[t], 0, 0, 0);
                acc[t] = __builtin_amdgcn_mfma_f32_16x16x32_bf16(Bl[t][s], xh[s], acc[t], 0, 0, 0);
            }
        }
        int node = tile * 16 + col;
        if (node < N) {
            #pragma unroll
            for (int t = 0; t < 2; t++) {
                union { ushort_t u[4]; uint2 v; } H, L;
                #pragma unroll
                for (int i = 0; i < 4; i++) {
                    float y = fmaxf(acc[t][i] + bvt[t][i], 0.f);
                    unsigned h16, l16;
                    bsplit(y, h16, l16);
                    H.u[i] = (ushort_t)h16;
                    L.u[i] = (ushort_t)l16;
                }
                size_t o = (size_t)node * EMB + (w * 2 + t) * 16 + kg * 4;
                *(uint2*)&Ohi[o] = H.v;
                *(uint2*)&Olo[o] = L.v;
            }
        }
    }
}

// ---------------- initial-readout linear as 1-ftile MFMA gemm: z[N,12] fp32 ----------------

__global__ __launch_bounds__(256) void k_zgemm(const ushort_t* __restrict__ Ahi,
        const ushort_t* __restrict__ Alo, float* __restrict__ z,
        const ushort_t* __restrict__ WzhiT, const ushort_t* __restrict__ WzloT,
        const float* __restrict__ biasz, int ntiles, int N) {
    const int w = threadIdx.x >> 6;
    const int lane = threadIdx.x & 63;
    const int col = lane & 15, kg = lane >> 4;

    bf16x8 Bh[4], Bl[4];
    #pragma unroll
    for (int s = 0; s < 4; s++) {
        int off = col * EMB + s * 32 + kg * 8;
        Bh[s] = *(const bf16x8*)(WzhiT + off);
        Bl[s] = *(const bf16x8*)(WzloT + off);
    }
    float4 bz = *(const float4*)&biasz[kg * 4];

    for (int tile = blockIdx.x * 4 + w; tile < ntiles; tile += gridDim.x * 4) {
        int na = min(tile * 16 + col, N - 1);
        const ushort_t* ph = Ahi + (size_t)na * EMB + kg * 8;
        const ushort_t* pl = Alo + (size_t)na * EMB + kg * 8;
        f32x4 acc = (f32x4){0.f, 0.f, 0.f, 0.f};
        #pragma unroll
        for (int s = 0; s < 4; s++) {
            bf16x8 xh = *(const bf16x8*)(ph + s * 32);
            bf16x8 xl = *(const bf16x8*)(pl + s * 32);
            acc = __builtin_amdgcn_mfma_f32_16x16x32_bf16(Bh[s], xh, acc, 0, 0, 0);
            acc = __builtin_amdgcn_mfma_f32_16x16x32_bf16(Bh[s], xl, acc, 0, 0, 0);
            acc = __builtin_amdgcn_mfma_f32_16x16x32_bf16(Bl[s], xh, acc, 0, 0, 0);
        }
        int node = tile * 16 + col;
        if (node < N && kg < 3) {
            float4 o = make_float4(acc[0] + bz.x, acc[1] + bz.y, acc[2] + bz.z, acc[3] + bz.w);
            *(float4*)&z[(size_t)node * CDIM + kg * 4] = o;
        }
    }
}

// ---------------- CSR aggregation fused with (1+eps)*h, hi/lo in & out ----------------

__global__ __launch_bounds__(256) void k_agg(const ushort_t* __restrict__ Hhi,
        const ushort_t* __restrict__ Hlo,
        ushort_t* __restrict__ Ohi, ushort_t* __restrict__ Olo,
        const int* __restrict__ rs, const int* __restrict__ csr_src,
        const float* __restrict__ epsp, int N) {
    int node = blockIdx.x * 8 + (threadIdx.x >> 5);
    if (node >= N) return;
    int lane = threadIdx.x & 31;
    float se = 1.f + epsp[0];
    size_t off = (size_t)node * EMB + lane * 4;
    uint2 sh = *(const uint2*)(Hhi + off);
    uint2 sl = *(const uint2*)(Hlo + off);
    float a0 = (bf_lo(sh.x) + bf_lo(sl.x)) * se;
    float a1 = (bf_hi(sh.x) + bf_hi(sl.x)) * se;
    float a2 = (bf_lo(sh.y) + bf_lo(sl.y)) * se;
    float a3 = (bf_hi(sh.y) + bf_hi(sl.y)) * se;
    int s0 = rs[node], e0 = rs[node + 1];
    for (int p = s0; p < e0; p++) {
        int sn = csr_src[p];
        size_t no = (size_t)sn * EMB + lane * 4;
        uint2 nh = *(const uint2*)(Hhi + no);
        uint2 nl = *(const uint2*)(Hlo + no);
        a0 += bf_lo(nh.x) + bf_lo(nl.x);
        a1 += bf_hi(nh.x) + bf_hi(nl.x);
        a2 += bf_lo(nh.y) + bf_lo(nl.y);
        a3 += bf_hi(nh.y) + bf_hi(nl.y);
    }
    unsigned h0, l0, h1, l1, h2, l2, h3, l3;
    bsplit(a0, h0, l0); bsplit(a1, h1, l1); bsplit(a2, h2, l2); bsplit(a3, h3, l3);
    uint2 H, L;
    H.x = h0 | (h1 << 16); H.y = h2 | (h3 << 16);
    L.x = l0 | (l1 << 16); L.y = l2 | (l3 << 16);
    *(uint2*)(Ohi + off) = H;
    *(uint2*)(Olo + off) = L;
}

// ---------------- readouts ----------------

__global__ __launch_bounds__(64) void k_zmax(const float* __restrict__ z, const int* __restrict__ gs,
        float* __restrict__ out, int G) {
    int g = blockIdx.x;
    int t = threadIdx.x;
    if (t >= CDIM) return;
    int s0 = gs[g], e0 = gs[g + 1];
    float m = -INFINITY;
    for (int n = s0; n < e0; n++) m = fmaxf(m, z[(size_t)n * CDIM + t]);
    out[g * CDIM + t] = m;
}

__global__ __launch_bounds__(128) void k_readout(const ushort_t* __restrict__ Hhi,
        const ushort_t* __restrict__ Hlo, const int* __restrict__ gs,
        const float* __restrict__ W, const float* __restrict__ lb,
        float* __restrict__ out, int G) {
    int g = blockIdx.x;
    int t = threadIdx.x;
    int s0 = gs[g], e0 = gs[g + 1];
    float mval = -INFINITY;
    for (int n = s0; n < e0; n++) {
        size_t o = (size_t)n * EMB + t;
        float v = bf_lo((unsigned)Hhi[o]) + bf_lo((unsigned)Hlo[o]);
        mval = fmaxf(mval, v);
    }
    __shared__ float mv[EMB];
    mv[t] = mval;
    __syncthreads();
    if (t < CDIM) {
        float acc = 0.f;
        for (int k = 0; k < EMB; k++) acc += mv[k] * W[k * CDIM + t];
        out[g * CDIM + t] += acc + lb[t];
    }
}

// ---------------- launch ----------------

extern "C" void kernel_launch(void* const* d_in, const int* in_sizes, int n_in,
                              void* d_out, int out_size, void* d_ws, size_t ws_size,
                              hipStream_t stream) {
    const float* x        = (const float*)d_in[0];
    const int*   ei       = (const int*)d_in[1];
    const int*   batch    = (const int*)d_in[2];
    const float* init_w1  = (const float*)d_in[3];
    const float* init_b1  = (const float*)d_in[4];
    const float* ibn1_s   = (const float*)d_in[5];
    const float* ibn1_b   = (const float*)d_in[6];
    const float* ibn1_m   = (const float*)d_in[7];
    const float* ibn1_v   = (const float*)d_in[8];
    const float* init_w2  = (const float*)d_in[9];
    const float* init_b2  = (const float*)d_in[10];
    const float* ibn2_s   = (const float*)d_in[11];
    const float* ibn2_b   = (const float*)d_in[12];
    const float* ibn2_m   = (const float*)d_in[13];
    const float* ibn2_v   = (const float*)d_in[14];
    const float* ilin_w   = (const float*)d_in[15];
    const float* ilin_b   = (const float*)d_in[16];
    const float* eps      = (const float*)d_in[17];
    const float* lw1      = (const float*)d_in[18];
    const float* lb1      = (const float*)d_in[19];
    const float* lbn1_s   = (const float*)d_in[20];
    const float* lbn1_b   = (const float*)d_in[21];
    const float* lbn1_m   = (const float*)d_in[22];
    const float* lbn1_v   = (const float*)d_in[23];
    const float* lw2      = (const float*)d_in[24];
    const float* lb2      = (const float*)d_in[25];
    const float* lbn2_s   = (const float*)d_in[26];
    const float* lbn2_b   = (const float*)d_in[27];
    const float* lbn2_m   = (const float*)d_in[28];
    const float* lbn2_v   = (const float*)d_in[29];
    const float* llin_w   = (const float*)d_in[30];
    const float* llin_b   = (const float*)d_in[31];

    const int N = in_sizes[0] / FIN;
    const int E = in_sizes[1] / 2;
    const int G = out_size / CDIM;
    const int* src = ei;
    const int* dst = ei + E;
    float* out = (float*)d_out;

    char* wp = (char*)d_ws;
    auto alloc = [&](size_t bytes) { char* p = wp; wp += (bytes + 255) & ~(size_t)255; return p; };
    ushort_t* WhiT  = (ushort_t*)alloc((size_t)11 * 16384 * 2);
    ushort_t* WloT  = (ushort_t*)alloc((size_t)11 * 16384 * 2);
    float*    biasf = (float*)alloc(11 * EMB * 4);
    float*    W1f   = (float*)alloc(FIN * EMB * 4);
    float*    bias1f= (float*)alloc(EMB * 4);
    ushort_t* WzhiT = (ushort_t*)alloc(16 * EMB * 2);
    ushort_t* WzloT = (ushort_t*)alloc(16 * EMB * 2);
    float*    biasz = (float*)alloc(16 * 4);
    int*      gs    = (int*)alloc((size_t)(G + 1) * 4);
    int*      rs    = (int*)alloc((size_t)(N + 1) * 4);
    int*      curoff= (int*)alloc((size_t)N * 4);
    int*      csr   = (int*)alloc((size_t)E * 4);
    int*      parts = (int*)alloc(256 * 4);
    ushort_t* Phi   = (ushort_t*)alloc((size_t)N * EMB * 2);
    ushort_t* Plo   = (ushort_t*)alloc((size_t)N * EMB * 2);
    ushort_t* Qhi   = (ushort_t*)alloc((size_t)N * EMB * 2);
    ushort_t* Qlo   = (ushort_t*)alloc((size_t)N * EMB * 2);
    float*    zbuf  = (float*)Phi;   // alias: P dead between init-gemm and first agg
    int*      cnt   = csr;           // alias: cnt dead before csr written

    const int NB = (N + 1023) / 1024;
    const int ntiles = (N + 15) / 16;

    // graph prep + weight prep
    k_zero_i32<<<(N + 255) / 256, 256, 0, stream>>>(cnt, N);
    k_hist<<<(E + 255) / 256, 256, 0, stream>>>(dst, cnt, E);
    k_scan1<<<NB, 256, 0, stream>>>(cnt, rs, parts, N);
    k_scan2<<<1, 256, 0, stream>>>(parts, NB);
    k_scan3<<<NB, 256, 0, stream>>>(rs, parts, curoff, N, E);
    k_fillslots<<<(E + 255) / 256, 256, 0, stream>>>(src, dst, curoff, csr, E);
    k_gstart<<<(N + 255) / 256, 256, 0, stream>>>(batch, gs, N, G);
    k_prep<<<13, 256, 0, stream>>>(init_w1, init_b1, ibn1_s, ibn1_b, ibn1_m, ibn1_v,
                                   init_w2, init_b2, ibn2_s, ibn2_b, ibn2_m, ibn2_v,
                                   lw1, lb1, lbn1_s, lbn1_b, lbn1_m, lbn1_v,
                                   lw2, lb2, lbn2_s, lbn2_b, lbn2_m, lbn2_v,
                                   ilin_w, ilin_b,
                                   WhiT, WloT, biasf, W1f, bias1f, WzhiT, WzloT, biasz);

    // init MLP
    k_lin16<<<(N + 15) / 16, 256, 0, stream>>>(x, Phi, Plo, W1f, bias1f, N);
    k_gemm<<<2560, 256, 0, stream>>>(Phi, Plo, Qhi, Qlo, WhiT, WloT, biasf, ntiles, N);

    // initial readout
    k_zgemm<<<1600, 256, 0, stream>>>(Qhi, Qlo, zbuf, WzhiT, WzloT, biasz, ntiles, N);
    k_zmax<<<G, 64, 0, stream>>>(zbuf, gs, out, G);

    ushort_t *curh = Qhi, *curl = Qlo, *othh = Phi, *othl = Plo;
    for (int l = 0; l < NLAYER; l++) {
        k_agg<<<(N + 7) / 8, 256, 0, stream>>>(curh, curl, othh, othl, rs, csr, eps + l, N);
        k_gemm<<<2560, 256, 0, stream>>>(othh, othl, curh, curl,
                                         WhiT + (size_t)(1 + l) * 16384, WloT + (size_t)(1 + l) * 16384,
                                         biasf + (1 + l) * EMB, ntiles, N);
        k_gemm<<<2560, 256, 0, stream>>>(curh, curl, othh, othl,
                                         WhiT + (size_t)(6 + l) * 16384, WloT + (size_t)(6 + l) * 16384,
                                         biasf + (6 + l) * EMB, ntiles, N);
        k_readout<<<G, 128, 0, stream>>>(othh, othl, gs, llin_w + l * EMB * CDIM,
                                         llin_b + l * CDIM, out, G);
        ushort_t* t;
        t = curh; curh = othh; othh = t;
        t = curl; curl = othl; othl = t;
    }
}

// Round 5
// 1198.420 us; speedup vs baseline: 1.2450x; 1.2450x over previous
//
#include <hip/hip_runtime.h>
#include <hip/hip_bf16.h>
#include <math.h>

#define EMB 128
#define CDIM 12
#define FIN 16
#define NLAYER 5
#define BN_EPS 1e-5f

typedef __attribute__((ext_vector_type(8))) short bf16x8;
typedef __attribute__((ext_vector_type(4))) float f32x4;
typedef unsigned short ushort_t;

__device__ __forceinline__ void bsplit(float y, unsigned& h16, unsigned& l16) {
    unsigned u = __float_as_uint(y);
    h16 = u >> 16;
    float r = y - __uint_as_float(u & 0xffff0000u);
    l16 = __float_as_uint(r) >> 16;
}

// LDS tile address: logical [node 0..15][byteoff 0..255], XOR-swizzled to kill
// the 256B-stride bank conflict on B-frag reads (16 lanes, same k-slice).
__device__ __forceinline__ unsigned swz(int node, int byteoff) {
    return (unsigned)((node * 256 + byteoff) ^ ((node & 7) << 4));
}

// ---------------- graph preprocessing ----------------

__global__ __launch_bounds__(256) void k_gstart(const int* __restrict__ batch,
                                                int* __restrict__ gs, int N, int G) {
    int i = blockIdx.x * 256 + threadIdx.x;
    if (i >= N) return;
    if (i == 0) gs[0] = 0;
    else { int b = batch[i]; if (b != batch[i - 1]) gs[b] = i; }
    if (i == N - 1) gs[G] = N;
}

__global__ __launch_bounds__(256) void k_zero_i32(int* __restrict__ p, int n) {
    int i = blockIdx.x * 256 + threadIdx.x;
    if (i < n) p[i] = 0;
}

__global__ __launch_bounds__(256) void k_hist(const int* __restrict__ dst, int* __restrict__ cnt, int E) {
    int e = blockIdx.x * 256 + threadIdx.x;
    if (e < E) atomicAdd(&cnt[dst[e]], 1);
}

__global__ __launch_bounds__(256) void k_scan1(const int* __restrict__ cnt, int* __restrict__ rs,
                                               int* __restrict__ partials, int N) {
    __shared__ int tsum[256];
    int t = threadIdx.x;
    int base = blockIdx.x * 1024 + t * 4;
    int c[4];
    #pragma unroll
    for (int j = 0; j < 4; j++) c[j] = (base + j < N) ? cnt[base + j] : 0;
    int s = c[0] + c[1] + c[2] + c[3];
    tsum[t] = s;
    __syncthreads();
    for (int off = 1; off < 256; off <<= 1) {
        int v = (t >= off) ? tsum[t - off] : 0;
        __syncthreads();
        tsum[t] += v;
        __syncthreads();
    }
    int run = tsum[t] - s;
    if (t == 255) partials[blockIdx.x] = tsum[255];
    #pragma unroll
    for (int j = 0; j < 4; j++) {
        if (base + j < N) rs[base + j] = run;
        run += c[j];
    }
}

__global__ __launch_bounds__(256) void k_scan2(int* __restrict__ partials, int NB) {
    __shared__ int tmp[256];
    int t = threadIdx.x;
    int v = (t < NB) ? partials[t] : 0;
    tmp[t] = v;
    __syncthreads();
    for (int off = 1; off < 256; off <<= 1) {
        int u = (t >= off) ? tmp[t - off] : 0;
        __syncthreads();
        tmp[t] += u;
        __syncthreads();
    }
    if (t < NB) partials[t] = tmp[t] - v;
}

__global__ __launch_bounds__(256) void k_scan3(int* __restrict__ rs, const int* __restrict__ partials,
                                               int* __restrict__ cur_off, int N, int E) {
    int t = threadIdx.x;
    int base = blockIdx.x * 1024 + t * 4;
    int add = partials[blockIdx.x];
    #pragma unroll
    for (int j = 0; j < 4; j++) {
        int i = base + j;
        if (i < N) { int v = rs[i] + add; rs[i] = v; cur_off[i] = v; }
    }
    if (blockIdx.x == 0 && t == 0) rs[N] = E;
}

__global__ __launch_bounds__(256) void k_fillslots(const int* __restrict__ src, const int* __restrict__ dst,
                                                   int* __restrict__ cur_off, int* __restrict__ csr_src, int E) {
    int e = blockIdx.x * 256 + threadIdx.x;
    if (e >= E) return;
    int d = dst[e];
    int pos = atomicAdd(&cur_off[d], 1);
    csr_src[pos] = src[e];
}

// ---------------- weight prep (same as R4) ----------------

__global__ __launch_bounds__(256) void k_prep(
        const float* __restrict__ init_w1, const float* __restrict__ init_b1,
        const float* __restrict__ b1s, const float* __restrict__ b1b,
        const float* __restrict__ b1m, const float* __restrict__ b1v,
        const float* __restrict__ init_w2, const float* __restrict__ init_b2,
        const float* __restrict__ i_s, const float* __restrict__ i_b,
        const float* __restrict__ i_m, const float* __restrict__ i_v,
        const float* __restrict__ lw1, const float* __restrict__ lb1,
        const float* __restrict__ l1s, const float* __restrict__ l1b,
        const float* __restrict__ l1m, const float* __restrict__ l1v,
        const float* __restrict__ lw2, const float* __restrict__ lb2,
        const float* __restrict__ l2s, const float* __restrict__ l2b,
        const float* __restrict__ l2m, const float* __restrict__ l2v,
        const float* __restrict__ ilin_w, const float* __restrict__ ilin_b,
        ushort_t* __restrict__ WhiT, ushort_t* __restrict__ WloT, float* __restrict__ biasf,
        float* __restrict__ W1f, float* __restrict__ bias1f,
        ushort_t* __restrict__ WzhiT, ushort_t* __restrict__ WzloT, float* __restrict__ biasz) {
    int j = blockIdx.x;
    int t = threadIdx.x;
    __shared__ float alpha[EMB];

    if (j == 12) {
        if (t < 16) biasz[t] = (t < CDIM) ? ilin_b[t] : 0.f;
        for (int i = t; i < 16 * EMB; i += 256) {
            int f = i >> 7, k = i & 127;
            float w = (f < CDIM) ? ilin_w[k * CDIM + f] : 0.f;
            unsigned h16, l16;
            bsplit(w, h16, l16);
            WzhiT[i] = (ushort_t)h16;
            WzloT[i] = (ushort_t)l16;
        }
        return;
    }
    if (j == 11) {
        if (t < EMB) {
            float a = b1s[t] * rsqrtf(b1v[t] + BN_EPS);
            alpha[t] = a;
            bias1f[t] = init_b1[t] * a + (b1b[t] - b1m[t] * a);
        }
        __syncthreads();
        for (int i = t; i < FIN * EMB; i += 256) W1f[i] = init_w1[i] * alpha[i & 127];
        return;
    }

    const float *W, *lb, *s, *bb, *m, *v;
    if (j == 0)      { W = init_w2;            lb = init_b2;        s = i_s;           bb = i_b;           m = i_m;           v = i_v; }
    else if (j <= 5) { int l = j - 1; W = lw1 + l * 16384; lb = lb1 + l * 128; s = l1s + l * 128; bb = l1b + l * 128; m = l1m + l * 128; v = l1v + l * 128; }
    else             { int l = j - 6; W = lw2 + l * 16384; lb = lb2 + l * 128; s = l2s + l * 128; bb = l2b + l * 128; m = l2m + l * 128; v = l2v + l * 128; }
    if (t < EMB) {
        float a = s[t] * rsqrtf(v[t] + BN_EPS);
        alpha[t] = a;
        biasf[j * EMB + t] = lb[t] * a + (bb[t] - m[t] * a);
    }
    __syncthreads();
    for (int i = t; i < EMB * EMB; i += 256) {
        int k = i >> 7, f = i & 127;
        float w = W[i] * alpha[f];
        unsigned h16, l16;
        bsplit(w, h16, l16);
        WhiT[j * 16384 + f * 128 + k] = (ushort_t)h16;
        WloT[j * 16384 + f * 128 + k] = (ushort_t)l16;
    }
}

// ---------------- fused layer kernel ----------------
// MODE 0 (init): phaseA = relu(bn(x@W1)) ; gemm(init_w2) -> h global + LDSB ; wave0: zgemm -> z
// MODE 1 (GIN):  phaseA = (1+eps)h + sum_nbr h (CSR gather) ; gemm1 -> LDSB ; gemm2 -> h' global
// 512 threads = 8 waves; wave w owns output f-tile w (16 feats); tile = 16 nodes.

template<int MODE>
__global__ __launch_bounds__(512) void k_layer(
        const float* __restrict__ hin, float* __restrict__ hout, float* __restrict__ z,
        const ushort_t* __restrict__ W1h, const ushort_t* __restrict__ W1l, const float* __restrict__ b1,
        const ushort_t* __restrict__ W2h, const ushort_t* __restrict__ W2l, const float* __restrict__ b2,
        const ushort_t* __restrict__ Wzh, const ushort_t* __restrict__ Wzl, const float* __restrict__ bz,
        const float* __restrict__ W1f, const float* __restrict__ b1f,
        const int* __restrict__ rs, const int* __restrict__ csr, const float* __restrict__ epsp,
        int ntiles, int N) {
    __shared__ ushort_t Ah[16 * 128], Al[16 * 128], Bh_[16 * 128], Bl_[16 * 128];
    __shared__ float W1s[FIN * EMB];

    const int t = threadIdx.x;
    const int w = t >> 6;
    const int lane = t & 63;
    const int col = lane & 15, kg = lane >> 4;
    const int nloc = t >> 5;        // phase-A node 0..15
    const int q = t & 31;           // phase-A feat slot; f0 = q*4

    if (MODE == 0) {
        for (int i = t; i < FIN * EMB; i += 512) W1s[i] = W1f[i];
        __syncthreads();
    }

    // register-resident weight fragments
    bf16x8 w1h[4], w1l[4], w2h[4], w2l[4], wzh[4], wzl[4];
    #pragma unroll
    for (int s = 0; s < 4; s++) {
        int off = (w * 16 + col) * EMB + s * 32 + kg * 8;
        w1h[s] = *(const bf16x8*)(W1h + off);
        w1l[s] = *(const bf16x8*)(W1l + off);
        if (MODE == 1) {
            w2h[s] = *(const bf16x8*)(W2h + off);
            w2l[s] = *(const bf16x8*)(W2l + off);
        }
        if (MODE == 0) {
            int zoff = col * EMB + s * 32 + kg * 8;
            wzh[s] = *(const bf16x8*)(Wzh + zoff);
            wzl[s] = *(const bf16x8*)(Wzl + zoff);
        }
    }
    float4 bv1 = *(const float4*)&b1[w * 16 + kg * 4];
    float4 bv2, bvz;
    if (MODE == 1) bv2 = *(const float4*)&b2[w * 16 + kg * 4];
    if (MODE == 0) bvz = *(const float4*)&bz[kg * 4];
    float se = (MODE == 1) ? (1.f + epsp[0]) : 0.f;
    float4 ba = (MODE == 0) ? *(const float4*)&b1f[q * 4] : make_float4(0.f, 0.f, 0.f, 0.f);

    for (int tile = blockIdx.x; tile < ntiles; tile += gridDim.x) {
        int node = tile * 16 + nloc;
        int nclamp = min(node, N - 1);

        // ---- phase A -> LDSA (hi/lo) ----
        float a0, a1, a2, a3;
        if (MODE == 1) {
            const float4* hp = (const float4*)hin;
            float4 sv = hp[(size_t)nclamp * 32 + q];
            a0 = sv.x * se; a1 = sv.y * se; a2 = sv.z * se; a3 = sv.w * se;
            int p0 = rs[nclamp], p1 = rs[nclamp + 1];
            for (int p = p0; p < p1; p++) {
                int sn = csr[p];
                float4 nv = hp[(size_t)sn * 32 + q];
                a0 += nv.x; a1 += nv.y; a2 += nv.z; a3 += nv.w;
            }
        } else {
            a0 = ba.x; a1 = ba.y; a2 = ba.z; a3 = ba.w;
            const float* xp = hin + (size_t)nclamp * FIN;
            #pragma unroll
            for (int k = 0; k < FIN; k++) {
                float xk = xp[k];
                float4 wv = *(const float4*)&W1s[k * EMB + q * 4];
                a0 += xk * wv.x; a1 += xk * wv.y; a2 += xk * wv.z; a3 += xk * wv.w;
            }
            a0 = fmaxf(a0, 0.f); a1 = fmaxf(a1, 0.f); a2 = fmaxf(a2, 0.f); a3 = fmaxf(a3, 0.f);
        }
        {
            unsigned h0, l0, h1, l1, h2, l2, h3, l3;
            bsplit(a0, h0, l0); bsplit(a1, h1, l1); bsplit(a2, h2, l2); bsplit(a3, h3, l3);
            uint2 H, L;
            H.x = h0 | (h1 << 16); H.y = h2 | (h3 << 16);
            L.x = l0 | (l1 << 16); L.y = l2 | (l3 << 16);
            unsigned ad = swz(nloc, q * 8);
            *(uint2*)((char*)Ah + ad) = H;
            *(uint2*)((char*)Al + ad) = L;
        }
        __syncthreads();

        // ---- phase B: gemm1 from LDSA ----
        {
            f32x4 accA = (f32x4){0.f, 0.f, 0.f, 0.f};
            f32x4 accB = (f32x4){0.f, 0.f, 0.f, 0.f};
            #pragma unroll
            for (int s = 0; s < 4; s++) {
                unsigned ad = swz(col, (s * 32 + kg * 8) * 2);
                bf16x8 xh = *(const bf16x8*)((const char*)Ah + ad);
                bf16x8 xl = *(const bf16x8*)((const char*)Al + ad);
                accA = __builtin_amdgcn_mfma_f32_16x16x32_bf16(w1h[s], xh, accA, 0, 0, 0);
                accB = __builtin_amdgcn_mfma_f32_16x16x32_bf16(w1h[s], xl, accB, 0, 0, 0);
                accB = __builtin_amdgcn_mfma_f32_16x16x32_bf16(w1l[s], xh, accB, 0, 0, 0);
            }
            float y0 = fmaxf(accA[0] + accB[0] + bv1.x, 0.f);
            float y1 = fmaxf(accA[1] + accB[1] + bv1.y, 0.f);
            float y2 = fmaxf(accA[2] + accB[2] + bv1.z, 0.f);
            float y3 = fmaxf(accA[3] + accB[3] + bv1.w, 0.f);
            int onode = tile * 16 + col;
            if (MODE == 0 && onode < N) {
                *(float4*)&hout[(size_t)onode * EMB + w * 16 + kg * 4] = make_float4(y0, y1, y2, y3);
            }
            unsigned h0, l0, h1, l1, h2, l2, h3, l3;
            bsplit(y0, h0, l0); bsplit(y1, h1, l1); bsplit(y2, h2, l2); bsplit(y3, h3, l3);
            uint2 H, L;
            H.x = h0 | (h1 << 16); H.y = h2 | (h3 << 16);
            L.x = l0 | (l1 << 16); L.y = l2 | (l3 << 16);
            unsigned ad = swz(col, w * 32 + kg * 8);
            *(uint2*)((char*)Bh_ + ad) = H;
            *(uint2*)((char*)Bl_ + ad) = L;
        }
        __syncthreads();

        // ---- phase D ----
        if (MODE == 1) {
            f32x4 accA = (f32x4){0.f, 0.f, 0.f, 0.f};
            f32x4 accB = (f32x4){0.f, 0.f, 0.f, 0.f};
            #pragma unroll
            for (int s = 0; s < 4; s++) {
                unsigned ad = swz(col, (s * 32 + kg * 8) * 2);
                bf16x8 xh = *(const bf16x8*)((const char*)Bh_ + ad);
                bf16x8 xl = *(const bf16x8*)((const char*)Bl_ + ad);
                accA = __builtin_amdgcn_mfma_f32_16x16x32_bf16(w2h[s], xh, accA, 0, 0, 0);
                accB = __builtin_amdgcn_mfma_f32_16x16x32_bf16(w2h[s], xl, accB, 0, 0, 0);
                accB = __builtin_amdgcn_mfma_f32_16x16x32_bf16(w2l[s], xh, accB, 0, 0, 0);
            }
            int onode = tile * 16 + col;
            if (onode < N) {
                float4 o;
                o.x = fmaxf(accA[0] + accB[0] + bv2.x, 0.f);
                o.y = fmaxf(accA[1] + accB[1] + bv2.y, 0.f);
                o.z = fmaxf(accA[2] + accB[2] + bv2.z, 0.f);
                o.w = fmaxf(accA[3] + accB[3] + bv2.w, 0.f);
                *(float4*)&hout[(size_t)onode * EMB + w * 16 + kg * 4] = o;
            }
        } else if (w == 0) {
            f32x4 accA = (f32x4){0.f, 0.f, 0.f, 0.f};
            f32x4 accB = (f32x4){0.f, 0.f, 0.f, 0.f};
            #pragma unroll
            for (int s = 0; s < 4; s++) {
                unsigned ad = swz(col, (s * 32 + kg * 8) * 2);
                bf16x8 xh = *(const bf16x8*)((const char*)Bh_ + ad);
                bf16x8 xl = *(const bf16x8*)((const char*)Bl_ + ad);
                accA = __builtin_amdgcn_mfma_f32_16x16x32_bf16(wzh[s], xh, accA, 0, 0, 0);
                accB = __builtin_amdgcn_mfma_f32_16x16x32_bf16(wzh[s], xl, accB, 0, 0, 0);
                accB = __builtin_amdgcn_mfma_f32_16x16x32_bf16(wzl[s], xh, accB, 0, 0, 0);
            }
            int onode = tile * 16 + col;
            if (onode < N && kg < 3) {
                float4 o;
                o.x = accA[0] + accB[0] + bvz.x;
                o.y = accA[1] + accB[1] + bvz.y;
                o.z = accA[2] + accB[2] + bvz.z;
                o.w = accA[3] + accB[3] + bvz.w;
                *(float4*)&z[(size_t)onode * CDIM + kg * 4] = o;
            }
        }
        __syncthreads();
    }
}

// ---------------- readouts ----------------

__global__ __launch_bounds__(64) void k_zmax(const float* __restrict__ z, const int* __restrict__ gs,
        float* __restrict__ out, int G) {
    int g = blockIdx.x;
    int t = threadIdx.x;
    if (t >= CDIM) return;
    int s0 = gs[g], e0 = gs[g + 1];
    float m = -INFINITY;
    for (int n = s0; n < e0; n++) m = fmaxf(m, z[(size_t)n * CDIM + t]);
    out[g * CDIM + t] = m;
}

__global__ __launch_bounds__(128) void k_readout(const float* __restrict__ h,
        const int* __restrict__ gs, const float* __restrict__ W,
        const float* __restrict__ lb, float* __restrict__ out, int G) {
    int g = blockIdx.x;
    int t = threadIdx.x;
    int s0 = gs[g], e0 = gs[g + 1];
    float mval = -INFINITY;
    for (int n = s0; n < e0; n++) mval = fmaxf(mval, h[(size_t)n * EMB + t]);
    __shared__ float mv[EMB];
    mv[t] = mval;
    __syncthreads();
    if (t < CDIM) {
        float acc = 0.f;
        for (int k = 0; k < EMB; k++) acc += mv[k] * W[k * CDIM + t];
        out[g * CDIM + t] += acc + lb[t];
    }
}

// ---------------- launch ----------------

extern "C" void kernel_launch(void* const* d_in, const int* in_sizes, int n_in,
                              void* d_out, int out_size, void* d_ws, size_t ws_size,
                              hipStream_t stream) {
    const float* x        = (const float*)d_in[0];
    const int*   ei       = (const int*)d_in[1];
    const int*   batch    = (const int*)d_in[2];
    const float* init_w1  = (const float*)d_in[3];
    const float* init_b1  = (const float*)d_in[4];
    const float* ibn1_s   = (const float*)d_in[5];
    const float* ibn1_b   = (const float*)d_in[6];
    const float* ibn1_m   = (const float*)d_in[7];
    const float* ibn1_v   = (const float*)d_in[8];
    const float* init_w2  = (const float*)d_in[9];
    const float* init_b2  = (const float*)d_in[10];
    const float* ibn2_s   = (const float*)d_in[11];
    const float* ibn2_b   = (const float*)d_in[12];
    const float* ibn2_m   = (const float*)d_in[13];
    const float* ibn2_v   = (const float*)d_in[14];
    const float* ilin_w   = (const float*)d_in[15];
    const float* ilin_b   = (const float*)d_in[16];
    const float* eps      = (const float*)d_in[17];
    const float* lw1      = (const float*)d_in[18];
    const float* lb1      = (const float*)d_in[19];
    const float* lbn1_s   = (const float*)d_in[20];
    const float* lbn1_b   = (const float*)d_in[21];
    const float* lbn1_m   = (const float*)d_in[22];
    const float* lbn1_v   = (const float*)d_in[23];
    const float* lw2      = (const float*)d_in[24];
    const float* lb2      = (const float*)d_in[25];
    const float* lbn2_s   = (const float*)d_in[26];
    const float* lbn2_b   = (const float*)d_in[27];
    const float* lbn2_m   = (const float*)d_in[28];
    const float* lbn2_v   = (const float*)d_in[29];
    const float* llin_w   = (const float*)d_in[30];
    const float* llin_b   = (const float*)d_in[31];

    const int N = in_sizes[0] / FIN;
    const int E = in_sizes[1] / 2;
    const int G = out_size / CDIM;
    const int* src = ei;
    const int* dst = ei + E;
    float* out = (float*)d_out;

    char* wp = (char*)d_ws;
    auto alloc = [&](size_t bytes) { char* p = wp; wp += (bytes + 255) & ~(size_t)255; return p; };
    ushort_t* WhiT  = (ushort_t*)alloc((size_t)11 * 16384 * 2);
    ushort_t* WloT  = (ushort_t*)alloc((size_t)11 * 16384 * 2);
    float*    biasf = (float*)alloc(11 * EMB * 4);
    float*    W1f   = (float*)alloc(FIN * EMB * 4);
    float*    bias1f= (float*)alloc(EMB * 4);
    ushort_t* WzhiT = (ushort_t*)alloc(16 * EMB * 2);
    ushort_t* WzloT = (ushort_t*)alloc(16 * EMB * 2);
    float*    biasz = (float*)alloc(16 * 4);
    int*      gs    = (int*)alloc((size_t)(G + 1) * 4);
    int*      rs    = (int*)alloc((size_t)(N + 1) * 4);
    int*      curoff= (int*)alloc((size_t)N * 4);
    int*      csr   = (int*)alloc((size_t)E * 4);
    int*      parts = (int*)alloc(256 * 4);
    float*    bufP  = (float*)alloc((size_t)N * EMB * 4);
    float*    bufQ  = (float*)alloc((size_t)N * EMB * 4);
    float*    zbuf  = bufP;          // alias: P unused until layer 0 output; zmax runs first
    int*      cnt   = csr;           // alias: cnt dead before csr written

    const int NB = (N + 1023) / 1024;
    const int ntiles = (N + 15) / 16;

    // graph prep + weight prep
    k_zero_i32<<<(N + 255) / 256, 256, 0, stream>>>(cnt, N);
    k_hist<<<(E + 255) / 256, 256, 0, stream>>>(dst, cnt, E);
    k_scan1<<<NB, 256, 0, stream>>>(cnt, rs, parts, N);
    k_scan2<<<1, 256, 0, stream>>>(parts, NB);
    k_scan3<<<NB, 256, 0, stream>>>(rs, parts, curoff, N, E);
    k_fillslots<<<(E + 255) / 256, 256, 0, stream>>>(src, dst, curoff, csr, E);
    k_gstart<<<(N + 255) / 256, 256, 0, stream>>>(batch, gs, N, G);
    k_prep<<<13, 256, 0, stream>>>(init_w1, init_b1, ibn1_s, ibn1_b, ibn1_m, ibn1_v,
                                   init_w2, init_b2, ibn2_s, ibn2_b, ibn2_m, ibn2_v,
                                   lw1, lb1, lbn1_s, lbn1_b, lbn1_m, lbn1_v,
                                   lw2, lb2, lbn2_s, lbn2_b, lbn2_m, lbn2_v,
                                   ilin_w, ilin_b,
                                   WhiT, WloT, biasf, W1f, bias1f, WzhiT, WzloT, biasz);

    // init MLP + z (fused) -> h in bufQ, z in zbuf
    k_layer<0><<<2560, 512, 0, stream>>>(x, bufQ, zbuf,
                                         WhiT, WloT, biasf,
                                         nullptr, nullptr, nullptr,
                                         WzhiT, WzloT, biasz,
                                         W1f, bias1f,
                                         nullptr, nullptr, nullptr, ntiles, N);
    k_zmax<<<G, 64, 0, stream>>>(zbuf, gs, out, G);

    float* cur = bufQ;
    float* oth = bufP;
    for (int l = 0; l < NLAYER; l++) {
        k_layer<1><<<2560, 512, 0, stream>>>(cur, oth, nullptr,
                                             WhiT + (size_t)(1 + l) * 16384, WloT + (size_t)(1 + l) * 16384, biasf + (1 + l) * EMB,
                                             WhiT + (size_t)(6 + l) * 16384, WloT + (size_t)(6 + l) * 16384, biasf + (6 + l) * EMB,
                                             nullptr, nullptr, nullptr,
                                             nullptr, nullptr,
                                             rs, csr, eps + l, ntiles, N);
        k_readout<<<G, 128, 0, stream>>>(oth, gs, llin_w + l * EMB * CDIM, llin_b + l * CDIM, out, G);
        float* tmp = cur; cur = oth; oth = tmp;
    }
}

// Round 6
// 936.464 us; speedup vs baseline: 1.5933x; 1.2797x over previous
//
#include <hip/hip_runtime.h>
#include <hip/hip_bf16.h>
#include <math.h>

#define EMB 128
#define CDIM 12
#define FIN 16
#define NLAYER 5
#define BN_EPS 1e-5f

typedef __attribute__((ext_vector_type(8))) short bf16x8;
typedef __attribute__((ext_vector_type(4))) float f32x4;
typedef unsigned short ushort_t;

__device__ __forceinline__ void bsplit(float y, unsigned& h16, unsigned& l16) {
    unsigned u = __float_as_uint(y);
    h16 = u >> 16;
    float r = y - __uint_as_float(u & 0xffff0000u);
    l16 = __float_as_uint(r) >> 16;
}

// LDS tile address: logical [node][byteoff 0..255], XOR-swizzled for bank spread.
__device__ __forceinline__ unsigned swz(int node, unsigned byteoff) {
    return (unsigned)(node * 256 + byteoff) ^ (((unsigned)node & 7u) << 4);
}

// ---------------- graph preprocessing ----------------

__global__ __launch_bounds__(256) void k_gstart(const int* __restrict__ batch,
                                                int* __restrict__ gs, int N, int G) {
    int i = blockIdx.x * 256 + threadIdx.x;
    if (i >= N) return;
    if (i == 0) gs[0] = 0;
    else { int b = batch[i]; if (b != batch[i - 1]) gs[b] = i; }
    if (i == N - 1) gs[G] = N;
}

__global__ __launch_bounds__(256) void k_zero_i32(int* __restrict__ p, int n) {
    int i = blockIdx.x * 256 + threadIdx.x;
    if (i < n) p[i] = 0;
}

__global__ __launch_bounds__(256) void k_hist(const int* __restrict__ dst, int* __restrict__ cnt, int E) {
    int e = blockIdx.x * 256 + threadIdx.x;
    if (e < E) atomicAdd(&cnt[dst[e]], 1);
}

__global__ __launch_bounds__(256) void k_scan1(const int* __restrict__ cnt, int* __restrict__ rs,
                                               int* __restrict__ partials, int N) {
    __shared__ int tsum[256];
    int t = threadIdx.x;
    int base = blockIdx.x * 1024 + t * 4;
    int c[4];
    #pragma unroll
    for (int j = 0; j < 4; j++) c[j] = (base + j < N) ? cnt[base + j] : 0;
    int s = c[0] + c[1] + c[2] + c[3];
    tsum[t] = s;
    __syncthreads();
    for (int off = 1; off < 256; off <<= 1) {
        int v = (t >= off) ? tsum[t - off] : 0;
        __syncthreads();
        tsum[t] += v;
        __syncthreads();
    }
    int run = tsum[t] - s;
    if (t == 255) partials[blockIdx.x] = tsum[255];
    #pragma unroll
    for (int j = 0; j < 4; j++) {
        if (base + j < N) rs[base + j] = run;
        run += c[j];
    }
}

__global__ __launch_bounds__(256) void k_scan2(int* __restrict__ partials, int NB) {
    __shared__ int tmp[256];
    int t = threadIdx.x;
    int v = (t < NB) ? partials[t] : 0;
    tmp[t] = v;
    __syncthreads();
    for (int off = 1; off < 256; off <<= 1) {
        int u = (t >= off) ? tmp[t - off] : 0;
        __syncthreads();
        tmp[t] += u;
        __syncthreads();
    }
    if (t < NB) partials[t] = tmp[t] - v;
}

__global__ __launch_bounds__(256) void k_scan3(int* __restrict__ rs, const int* __restrict__ partials,
                                               int* __restrict__ cur_off, int N, int E) {
    int t = threadIdx.x;
    int base = blockIdx.x * 1024 + t * 4;
    int add = partials[blockIdx.x];
    #pragma unroll
    for (int j = 0; j < 4; j++) {
        int i = base + j;
        if (i < N) { int v = rs[i] + add; rs[i] = v; cur_off[i] = v; }
    }
    if (blockIdx.x == 0 && t == 0) rs[N] = E;
}

__global__ __launch_bounds__(256) void k_fillslots(const int* __restrict__ src, const int* __restrict__ dst,
                                                   int* __restrict__ cur_off, int* __restrict__ csr_src, int E) {
    int e = blockIdx.x * 256 + threadIdx.x;
    if (e >= E) return;
    int d = dst[e];
    int pos = atomicAdd(&cur_off[d], 1);
    csr_src[pos] = src[e];
}

// ---------------- weight prep ----------------

__global__ __launch_bounds__(256) void k_prep(
        const float* __restrict__ init_w1, const float* __restrict__ init_b1,
        const float* __restrict__ b1s, const float* __restrict__ b1b,
        const float* __restrict__ b1m, const float* __restrict__ b1v,
        const float* __restrict__ init_w2, const float* __restrict__ init_b2,
        const float* __restrict__ i_s, const float* __restrict__ i_b,
        const float* __restrict__ i_m, const float* __restrict__ i_v,
        const float* __restrict__ lw1, const float* __restrict__ lb1,
        const float* __restrict__ l1s, const float* __restrict__ l1b,
        const float* __restrict__ l1m, const float* __restrict__ l1v,
        const float* __restrict__ lw2, const float* __restrict__ lb2,
        const float* __restrict__ l2s, const float* __restrict__ l2b,
        const float* __restrict__ l2m, const float* __restrict__ l2v,
        const float* __restrict__ ilin_w, const float* __restrict__ ilin_b,
        ushort_t* __restrict__ WhiT, ushort_t* __restrict__ WloT, float* __restrict__ biasf,
        float* __restrict__ W1f, float* __restrict__ bias1f,
        ushort_t* __restrict__ WzhiT, ushort_t* __restrict__ WzloT, float* __restrict__ biasz) {
    int j = blockIdx.x;
    int t = threadIdx.x;
    __shared__ float alpha[EMB];

    if (j == 12) {
        if (t < 16) biasz[t] = (t < CDIM) ? ilin_b[t] : 0.f;
        for (int i = t; i < 16 * EMB; i += 256) {
            int f = i >> 7, k = i & 127;
            float w = (f < CDIM) ? ilin_w[k * CDIM + f] : 0.f;
            unsigned h16, l16;
            bsplit(w, h16, l16);
            WzhiT[i] = (ushort_t)h16;
            WzloT[i] = (ushort_t)l16;
        }
        return;
    }
    if (j == 11) {
        if (t < EMB) {
            float a = b1s[t] * rsqrtf(b1v[t] + BN_EPS);
            alpha[t] = a;
            bias1f[t] = init_b1[t] * a + (b1b[t] - b1m[t] * a);
        }
        __syncthreads();
        for (int i = t; i < FIN * EMB; i += 256) W1f[i] = init_w1[i] * alpha[i & 127];
        return;
    }

    const float *W, *lb, *s, *bb, *m, *v;
    if (j == 0)      { W = init_w2;            lb = init_b2;        s = i_s;           bb = i_b;           m = i_m;           v = i_v; }
    else if (j <= 5) { int l = j - 1; W = lw1 + l * 16384; lb = lb1 + l * 128; s = l1s + l * 128; bb = l1b + l * 128; m = l1m + l * 128; v = l1v + l * 128; }
    else             { int l = j - 6; W = lw2 + l * 16384; lb = lb2 + l * 128; s = l2s + l * 128; bb = l2b + l * 128; m = l2m + l * 128; v = l2v + l * 128; }
    if (t < EMB) {
        float a = s[t] * rsqrtf(v[t] + BN_EPS);
        alpha[t] = a;
        biasf[j * EMB + t] = lb[t] * a + (bb[t] - m[t] * a);
    }
    __syncthreads();
    for (int i = t; i < EMB * EMB; i += 256) {
        int k = i >> 7, f = i & 127;
        float w = W[i] * alpha[f];
        unsigned h16, l16;
        bsplit(w, h16, l16);
        WhiT[j * 16384 + f * 128 + k] = (ushort_t)h16;
        WloT[j * 16384 + f * 128 + k] = (ushort_t)l16;
    }
}

// ---------------- fused layer kernel ----------------
// MODE 0 (init, NT=16): phaseA = relu(bn(x@W1)); gemm(init_w2) -> h global + LDSB; wave0: z-gemm
// MODE 1 (GIN, NT=32):  phaseA = (1+eps)h + sum_nbr h (CSR, unroll-4); gemm1 -> LDSB; gemm2 -> h'
// 512 threads = 8 waves; wave w owns 16 output feats; 2 barriers per tile.

template<int MODE>
__global__ __launch_bounds__(512, 4) void k_layer(
        const float* __restrict__ hin, float* __restrict__ hout, float* __restrict__ z,
        const ushort_t* __restrict__ W1h, const ushort_t* __restrict__ W1l, const float* __restrict__ b1,
        const ushort_t* __restrict__ W2h, const ushort_t* __restrict__ W2l, const float* __restrict__ b2,
        const ushort_t* __restrict__ Wzh, const ushort_t* __restrict__ Wzl, const float* __restrict__ bz,
        const float* __restrict__ W1f, const float* __restrict__ b1f,
        const int* __restrict__ rs, const int* __restrict__ csr, const float* __restrict__ epsp,
        int ntiles, int N) {
    constexpr int NT = (MODE == 1) ? 32 : 16;
    __shared__ ushort_t Ah[NT * 128], Al[NT * 128], Bh_[NT * 128], Bl_[NT * 128];
    __shared__ float W1s[(MODE == 0) ? FIN * EMB : 1];

    const int t = threadIdx.x;
    const int w = t >> 6;
    const int lane = t & 63;
    const int col = lane & 15, kg = lane >> 4;

    if (MODE == 0) {
        for (int i = t; i < FIN * EMB; i += 512) W1s[i] = W1f[i];
        __syncthreads();
    }

    // register-resident weight fragments
    bf16x8 w1h[4], w1l[4], w2h[4], w2l[4], wzh[4], wzl[4];
    #pragma unroll
    for (int s = 0; s < 4; s++) {
        int off = (w * 16 + col) * EMB + s * 32 + kg * 8;
        w1h[s] = *(const bf16x8*)(W1h + off);
        w1l[s] = *(const bf16x8*)(W1l + off);
        if (MODE == 1) {
            w2h[s] = *(const bf16x8*)(W2h + off);
            w2l[s] = *(const bf16x8*)(W2l + off);
        }
        if (MODE == 0) {
            int zoff = col * EMB + s * 32 + kg * 8;
            wzh[s] = *(const bf16x8*)(Wzh + zoff);
            wzl[s] = *(const bf16x8*)(Wzl + zoff);
        }
    }
    float4 bv1 = *(const float4*)&b1[w * 16 + kg * 4];
    float4 bv2, bvz;
    if (MODE == 1) bv2 = *(const float4*)&b2[w * 16 + kg * 4];
    if (MODE == 0) bvz = *(const float4*)&bz[kg * 4];
    float se = (MODE == 1) ? (1.f + epsp[0]) : 0.f;

    for (int tile = blockIdx.x; tile < ntiles; tile += gridDim.x) {
        const int n0 = tile * NT;

        // ---- phase A -> LDSA (hi/lo) ----
        if (MODE == 1) {
            const int nl = t >> 4, q2 = t & 15;   // node-local 0..31, 8 feats
            const int nc = min(n0 + nl, N - 1);
            const float4* hp = (const float4*)hin;
            const size_t rq = (size_t)nc * 32 + q2 * 2;
            float4 s0 = hp[rq], s1 = hp[rq + 1];
            float a0 = s0.x * se, a1 = s0.y * se, a2 = s0.z * se, a3 = s0.w * se;
            float a4 = s1.x * se, a5 = s1.y * se, a6 = s1.z * se, a7 = s1.w * se;
            int p = rs[nc], pe = rs[nc + 1];
            for (; p + 4 <= pe; p += 4) {
                int i0 = csr[p], i1 = csr[p + 1], i2 = csr[p + 2], i3 = csr[p + 3];
                size_t o0 = (size_t)i0 * 32 + q2 * 2, o1 = (size_t)i1 * 32 + q2 * 2;
                size_t o2 = (size_t)i2 * 32 + q2 * 2, o3 = (size_t)i3 * 32 + q2 * 2;
                float4 v0 = hp[o0], u0 = hp[o0 + 1];
                float4 v1 = hp[o1], u1 = hp[o1 + 1];
                float4 v2 = hp[o2], u2 = hp[o2 + 1];
                float4 v3 = hp[o3], u3 = hp[o3 + 1];
                a0 += v0.x + v1.x + v2.x + v3.x;  a1 += v0.y + v1.y + v2.y + v3.y;
                a2 += v0.z + v1.z + v2.z + v3.z;  a3 += v0.w + v1.w + v2.w + v3.w;
                a4 += u0.x + u1.x + u2.x + u3.x;  a5 += u0.y + u1.y + u2.y + u3.y;
                a6 += u0.z + u1.z + u2.z + u3.z;  a7 += u0.w + u1.w + u2.w + u3.w;
            }
            for (; p < pe; ++p) {
                int sn = csr[p];
                size_t o = (size_t)sn * 32 + q2 * 2;
                float4 v = hp[o], u = hp[o + 1];
                a0 += v.x; a1 += v.y; a2 += v.z; a3 += v.w;
                a4 += u.x; a5 += u.y; a6 += u.z; a7 += u.w;
            }
            unsigned h[8], l[8];
            bsplit(a0, h[0], l[0]); bsplit(a1, h[1], l[1]);
            bsplit(a2, h[2], l[2]); bsplit(a3, h[3], l[3]);
            bsplit(a4, h[4], l[4]); bsplit(a5, h[5], l[5]);
            bsplit(a6, h[6], l[6]); bsplit(a7, h[7], l[7]);
            uint4 H, L;
            H.x = h[0] | (h[1] << 16); H.y = h[2] | (h[3] << 16);
            H.z = h[4] | (h[5] << 16); H.w = h[6] | (h[7] << 16);
            L.x = l[0] | (l[1] << 16); L.y = l[2] | (l[3] << 16);
            L.z = l[4] | (l[5] << 16); L.w = l[6] | (l[7] << 16);
            unsigned ad = swz(nl, (unsigned)q2 * 16);
            *(uint4*)((char*)Ah + ad) = H;
            *(uint4*)((char*)Al + ad) = L;
        } else {
            const int nl = t >> 5, q = t & 31;    // 16 nodes x 4 feats
            const int nc = min(n0 + nl, N - 1);
            float4 ba = *(const float4*)&b1f[q * 4];
            float a0 = ba.x, a1 = ba.y, a2 = ba.z, a3 = ba.w;
            const float* xp = hin + (size_t)nc * FIN;
            #pragma unroll
            for (int k = 0; k < FIN; k++) {
                float xk = xp[k];
                float4 wv = *(const float4*)&W1s[k * EMB + q * 4];
                a0 += xk * wv.x; a1 += xk * wv.y; a2 += xk * wv.z; a3 += xk * wv.w;
            }
            a0 = fmaxf(a0, 0.f); a1 = fmaxf(a1, 0.f); a2 = fmaxf(a2, 0.f); a3 = fmaxf(a3, 0.f);
            unsigned h0, l0, h1, l1, h2, l2, h3, l3;
            bsplit(a0, h0, l0); bsplit(a1, h1, l1); bsplit(a2, h2, l2); bsplit(a3, h3, l3);
            uint2 H, L;
            H.x = h0 | (h1 << 16); H.y = h2 | (h3 << 16);
            L.x = l0 | (l1 << 16); L.y = l2 | (l3 << 16);
            unsigned ad = swz(nl, (unsigned)q * 8);
            *(uint2*)((char*)Ah + ad) = H;
            *(uint2*)((char*)Al + ad) = L;
        }
        __syncthreads();

        // ---- phase B: gemm1 from LDSA -> LDSB (MODE0: + hout store) ----
        {
            f32x4 aA0 = (f32x4){0.f, 0.f, 0.f, 0.f}, aB0 = aA0, aA1 = aA0, aB1 = aA0;
            #pragma unroll
            for (int s = 0; s < 4; s++) {
                unsigned bo = (unsigned)((s * 32 + kg * 8) * 2);
                bf16x8 xh0 = *(const bf16x8*)((const char*)Ah + swz(col, bo));
                bf16x8 xl0 = *(const bf16x8*)((const char*)Al + swz(col, bo));
                aA0 = __builtin_amdgcn_mfma_f32_16x16x32_bf16(w1h[s], xh0, aA0, 0, 0, 0);
                aB0 = __builtin_amdgcn_mfma_f32_16x16x32_bf16(w1h[s], xl0, aB0, 0, 0, 0);
                aB0 = __builtin_amdgcn_mfma_f32_16x16x32_bf16(w1l[s], xh0, aB0, 0, 0, 0);
                if (MODE == 1) {
                    bf16x8 xh1 = *(const bf16x8*)((const char*)Ah + swz(col + 16, bo));
                    bf16x8 xl1 = *(const bf16x8*)((const char*)Al + swz(col + 16, bo));
                    aA1 = __builtin_amdgcn_mfma_f32_16x16x32_bf16(w1h[s], xh1, aA1, 0, 0, 0);
                    aB1 = __builtin_amdgcn_mfma_f32_16x16x32_bf16(w1h[s], xl1, aB1, 0, 0, 0);
                    aB1 = __builtin_amdgcn_mfma_f32_16x16x32_bf16(w1l[s], xh1, aB1, 0, 0, 0);
                }
            }
            #pragma unroll
            for (int sub = 0; sub < ((MODE == 1) ? 2 : 1); sub++) {
                f32x4 aa = sub ? aA1 : aA0, ab = sub ? aB1 : aB0;
                float y0 = fmaxf(aa[0] + ab[0] + bv1.x, 0.f);
                float y1 = fmaxf(aa[1] + ab[1] + bv1.y, 0.f);
                float y2 = fmaxf(aa[2] + ab[2] + bv1.z, 0.f);
                float y3 = fmaxf(aa[3] + ab[3] + bv1.w, 0.f);
                if (MODE == 0) {
                    int onode = n0 + col;
                    if (onode < N)
                        *(float4*)&hout[(size_t)onode * EMB + w * 16 + kg * 4] = make_float4(y0, y1, y2, y3);
                }
                unsigned h0, l0, h1, l1, h2, l2, h3, l3;
                bsplit(y0, h0, l0); bsplit(y1, h1, l1); bsplit(y2, h2, l2); bsplit(y3, h3, l3);
                uint2 H, L;
                H.x = h0 | (h1 << 16); H.y = h2 | (h3 << 16);
                L.x = l0 | (l1 << 16); L.y = l2 | (l3 << 16);
                unsigned ad = swz(col + sub * 16, (unsigned)(w * 32 + kg * 8));
                *(uint2*)((char*)Bh_ + ad) = H;
                *(uint2*)((char*)Bl_ + ad) = L;
            }
        }
        __syncthreads();

        // ---- phase D: gemm2 (MODE1) / z-gemm (MODE0, wave0) ----
        if (MODE == 1) {
            f32x4 aA0 = (f32x4){0.f, 0.f, 0.f, 0.f}, aB0 = aA0, aA1 = aA0, aB1 = aA0;
            #pragma unroll
            for (int s = 0; s < 4; s++) {
                unsigned bo = (unsigned)((s * 32 + kg * 8) * 2);
                bf16x8 xh0 = *(const bf16x8*)((const char*)Bh_ + swz(col, bo));
                bf16x8 xl0 = *(const bf16x8*)((const char*)Bl_ + swz(col, bo));
                bf16x8 xh1 = *(const bf16x8*)((const char*)Bh_ + swz(col + 16, bo));
                bf16x8 xl1 = *(const bf16x8*)((const char*)Bl_ + swz(col + 16, bo));
                aA0 = __builtin_amdgcn_mfma_f32_16x16x32_bf16(w2h[s], xh0, aA0, 0, 0, 0);
                aB0 = __builtin_amdgcn_mfma_f32_16x16x32_bf16(w2h[s], xl0, aB0, 0, 0, 0);
                aB0 = __builtin_amdgcn_mfma_f32_16x16x32_bf16(w2l[s], xh0, aB0, 0, 0, 0);
                aA1 = __builtin_amdgcn_mfma_f32_16x16x32_bf16(w2h[s], xh1, aA1, 0, 0, 0);
                aB1 = __builtin_amdgcn_mfma_f32_16x16x32_bf16(w2h[s], xl1, aB1, 0, 0, 0);
                aB1 = __builtin_amdgcn_mfma_f32_16x16x32_bf16(w2l[s], xh1, aB1, 0, 0, 0);
            }
            #pragma unroll
            for (int sub = 0; sub < 2; sub++) {
                f32x4 aa = sub ? aA1 : aA0, ab = sub ? aB1 : aB0;
                int onode = n0 + col + sub * 16;
                if (onode < N) {
                    float4 o;
                    o.x = fmaxf(aa[0] + ab[0] + bv2.x, 0.f);
                    o.y = fmaxf(aa[1] + ab[1] + bv2.y, 0.f);
                    o.z = fmaxf(aa[2] + ab[2] + bv2.z, 0.f);
                    o.w = fmaxf(aa[3] + ab[3] + bv2.w, 0.f);
                    *(float4*)&hout[(size_t)onode * EMB + w * 16 + kg * 4] = o;
                }
            }
        } else if (w == 0) {
            f32x4 aA0 = (f32x4){0.f, 0.f, 0.f, 0.f}, aB0 = aA0;
            #pragma unroll
            for (int s = 0; s < 4; s++) {
                unsigned bo = (unsigned)((s * 32 + kg * 8) * 2);
                bf16x8 xh = *(const bf16x8*)((const char*)Bh_ + swz(col, bo));
                bf16x8 xl = *(const bf16x8*)((const char*)Bl_ + swz(col, bo));
                aA0 = __builtin_amdgcn_mfma_f32_16x16x32_bf16(wzh[s], xh, aA0, 0, 0, 0);
                aB0 = __builtin_amdgcn_mfma_f32_16x16x32_bf16(wzh[s], xl, aB0, 0, 0, 0);
                aB0 = __builtin_amdgcn_mfma_f32_16x16x32_bf16(wzl[s], xh, aB0, 0, 0, 0);
            }
            int onode = n0 + col;
            if (onode < N && kg < 3) {
                float4 o;
                o.x = aA0[0] + aB0[0] + bvz.x;
                o.y = aA0[1] + aB0[1] + bvz.y;
                o.z = aA0[2] + aB0[2] + bvz.z;
                o.w = aA0[3] + aB0[3] + bvz.w;
                *(float4*)&z[(size_t)onode * CDIM + kg * 4] = o;
            }
        }
        // no barrier here: next phase-A writes touch only the A-area, whose readers
        // (this tile's phase B) all passed the post-B barrier; B-area writes of the
        // next tile are gated by the next post-A barrier.
    }
}

// ---------------- readouts ----------------

__global__ __launch_bounds__(64) void k_zmax(const float* __restrict__ z, const int* __restrict__ gs,
        float* __restrict__ out, int G) {
    int g = blockIdx.x;
    int t = threadIdx.x;
    if (t >= CDIM) return;
    int s0 = gs[g], e0 = gs[g + 1];
    float m = -INFINITY;
    for (int n = s0; n < e0; n++) m = fmaxf(m, z[(size_t)n * CDIM + t]);
    out[g * CDIM + t] = m;
}

__global__ __launch_bounds__(128) void k_readout(const float* __restrict__ h,
        const int* __restrict__ gs, const float* __restrict__ W,
        const float* __restrict__ lb, float* __restrict__ out, int G) {
    int g = blockIdx.x;
    int t = threadIdx.x;
    int s0 = gs[g], e0 = gs[g + 1];
    float mval = -INFINITY;
    for (int n = s0; n < e0; n++) mval = fmaxf(mval, h[(size_t)n * EMB + t]);
    __shared__ float mv[EMB];
    mv[t] = mval;
    __syncthreads();
    if (t < CDIM) {
        float acc = 0.f;
        for (int k = 0; k < EMB; k++) acc += mv[k] * W[k * CDIM + t];
        out[g * CDIM + t] += acc + lb[t];
    }
}

// ---------------- launch ----------------

extern "C" void kernel_launch(void* const* d_in, const int* in_sizes, int n_in,
                              void* d_out, int out_size, void* d_ws, size_t ws_size,
                              hipStream_t stream) {
    const float* x        = (const float*)d_in[0];
    const int*   ei       = (const int*)d_in[1];
    const int*   batch    = (const int*)d_in[2];
    const float* init_w1  = (const float*)d_in[3];
    const float* init_b1  = (const float*)d_in[4];
    const float* ibn1_s   = (const float*)d_in[5];
    const float* ibn1_b   = (const float*)d_in[6];
    const float* ibn1_m   = (const float*)d_in[7];
    const float* ibn1_v   = (const float*)d_in[8];
    const float* init_w2  = (const float*)d_in[9];
    const float* init_b2  = (const float*)d_in[10];
    const float* ibn2_s   = (const float*)d_in[11];
    const float* ibn2_b   = (const float*)d_in[12];
    const float* ibn2_m   = (const float*)d_in[13];
    const float* ibn2_v   = (const float*)d_in[14];
    const float* ilin_w   = (const float*)d_in[15];
    const float* ilin_b   = (const float*)d_in[16];
    const float* eps      = (const float*)d_in[17];
    const float* lw1      = (const float*)d_in[18];
    const float* lb1      = (const float*)d_in[19];
    const float* lbn1_s   = (const float*)d_in[20];
    const float* lbn1_b   = (const float*)d_in[21];
    const float* lbn1_m   = (const float*)d_in[22];
    const float* lbn1_v   = (const float*)d_in[23];
    const float* lw2      = (const float*)d_in[24];
    const float* lb2      = (const float*)d_in[25];
    const float* lbn2_s   = (const float*)d_in[26];
    const float* lbn2_b   = (const float*)d_in[27];
    const float* lbn2_m   = (const float*)d_in[28];
    const float* lbn2_v   = (const float*)d_in[29];
    const float* llin_w   = (const float*)d_in[30];
    const float* llin_b   = (const float*)d_in[31];

    const int N = in_sizes[0] / FIN;
    const int E = in_sizes[1] / 2;
    const int G = out_size / CDIM;
    const int* src = ei;
    const int* dst = ei + E;
    float* out = (float*)d_out;

    char* wp = (char*)d_ws;
    auto alloc = [&](size_t bytes) { char* p = wp; wp += (bytes + 255) & ~(size_t)255; return p; };
    ushort_t* WhiT  = (ushort_t*)alloc((size_t)11 * 16384 * 2);
    ushort_t* WloT  = (ushort_t*)alloc((size_t)11 * 16384 * 2);
    float*    biasf = (float*)alloc(11 * EMB * 4);
    float*    W1f   = (float*)alloc(FIN * EMB * 4);
    float*    bias1f= (float*)alloc(EMB * 4);
    ushort_t* WzhiT = (ushort_t*)alloc(16 * EMB * 2);
    ushort_t* WzloT = (ushort_t*)alloc(16 * EMB * 2);
    float*    biasz = (float*)alloc(16 * 4);
    int*      gs    = (int*)alloc((size_t)(G + 1) * 4);
    int*      rs    = (int*)alloc((size_t)(N + 1) * 4);
    int*      curoff= (int*)alloc((size_t)N * 4);
    int*      csr   = (int*)alloc((size_t)E * 4);
    int*      parts = (int*)alloc(256 * 4);
    float*    bufP  = (float*)alloc((size_t)N * EMB * 4);
    float*    bufQ  = (float*)alloc((size_t)N * EMB * 4);
    float*    zbuf  = bufP;          // alias: P unused until layer-0 output; zmax runs first
    int*      cnt   = csr;           // alias: cnt dead before csr written

    const int NB = (N + 1023) / 1024;
    const int ntiles16 = (N + 15) / 16;
    const int ntiles32 = (N + 31) / 32;

    // graph prep + weight prep
    k_zero_i32<<<(N + 255) / 256, 256, 0, stream>>>(cnt, N);
    k_hist<<<(E + 255) / 256, 256, 0, stream>>>(dst, cnt, E);
    k_scan1<<<NB, 256, 0, stream>>>(cnt, rs, parts, N);
    k_scan2<<<1, 256, 0, stream>>>(parts, NB);
    k_scan3<<<NB, 256, 0, stream>>>(rs, parts, curoff, N, E);
    k_fillslots<<<(E + 255) / 256, 256, 0, stream>>>(src, dst, curoff, csr, E);
    k_gstart<<<(N + 255) / 256, 256, 0, stream>>>(batch, gs, N, G);
    k_prep<<<13, 256, 0, stream>>>(init_w1, init_b1, ibn1_s, ibn1_b, ibn1_m, ibn1_v,
                                   init_w2, init_b2, ibn2_s, ibn2_b, ibn2_m, ibn2_v,
                                   lw1, lb1, lbn1_s, lbn1_b, lbn1_m, lbn1_v,
                                   lw2, lb2, lbn2_s, lbn2_b, lbn2_m, lbn2_v,
                                   ilin_w, ilin_b,
                                   WhiT, WloT, biasf, W1f, bias1f, WzhiT, WzloT, biasz);

    // init MLP + z (fused) -> h in bufQ, z in zbuf
    k_layer<0><<<2048, 512, 0, stream>>>(x, bufQ, zbuf,
                                         WhiT, WloT, biasf,
                                         nullptr, nullptr, nullptr,
                                         WzhiT, WzloT, biasz,
                                         W1f, bias1f,
                                         nullptr, nullptr, nullptr, ntiles16, N);
    k_zmax<<<G, 64, 0, stream>>>(zbuf, gs, out, G);

    float* cur = bufQ;
    float* oth = bufP;
    for (int l = 0; l < NLAYER; l++) {
        k_layer<1><<<2048, 512, 0, stream>>>(cur, oth, nullptr,
                                             WhiT + (size_t)(1 + l) * 16384, WloT + (size_t)(1 + l) * 16384, biasf + (1 + l) * EMB,
                                             WhiT + (size_t)(6 + l) * 16384, WloT + (size_t)(6 + l) * 16384, biasf + (6 + l) * EMB,
                                             nullptr, nullptr, nullptr,
                                             nullptr, nullptr,
                                             rs, csr, eps + l, ntiles32, N);
        k_readout<<<G, 128, 0, stream>>>(oth, gs, llin_w + l * EMB * CDIM, llin_b + l * CDIM, out, G);
        float* tmp = cur; cur = oth; oth = tmp;
    }
}